// Round 1
// baseline (932.396 us; speedup 1.0000x reference)
//
#include <hip/hip_runtime.h>

#define ALPHA_C 0.9f
#define EPS_C 1e-3f

// Problem sizes (fixed)
//   B=32768, D=512, H=64
// ws layout (float offsets)
#define OFF_F     0ull
#define OFF_GVU   16777216ull   // U first, then GV overwrites (U consumed before GV written)
#define OFF_H1    33554432ull
#define OFF_H2    35651584ull
#define OFF_G1T2  37748736ull   // G1, later reused for T2
#define OFF_S2    39845888ull
#define OFF_LYAP  41943040ull
#define OFF_NUM   41975808ull
#define OFF_DPART 42008576ull   // 256 floats

// ---------------------------------------------------------------------------
// K1: H1 = relu(X W1 + b1), H2 = relu(H1 W2 + b2)   [B,64] each
// block: 256 thr, 16 samples; K=512 chunked by 128
__global__ __launch_bounds__(256) void k_h12(
    const float* __restrict__ x, const float* __restrict__ W1, const float* __restrict__ b1,
    const float* __restrict__ W2, const float* __restrict__ b2,
    float* __restrict__ H1, float* __restrict__ H2) {
  __shared__ float wch[128 * 64];   // W1 chunk, [k][j]
  __shared__ float xch[16 * 128];   // x chunk, [s][k]
  __shared__ float W2s[64 * 64];    // [k][j]
  __shared__ float h1s[16 * 64];
  const int tid = threadIdx.x;
  const int j = tid & 63, sub = tid >> 6;
  const int m0 = blockIdx.x * 16;

  #pragma unroll
  for (int c = 0; c < 16; ++c) W2s[c * 256 + tid] = W2[c * 256 + tid];

  float acc[4] = {0.f, 0.f, 0.f, 0.f};
  for (int k0 = 0; k0 < 512; k0 += 128) {
    __syncthreads();
    #pragma unroll
    for (int c = 0; c < 32; ++c) wch[c * 256 + tid] = W1[(size_t)k0 * 64 + c * 256 + tid];
    #pragma unroll
    for (int c = 0; c < 8; ++c) {
      int idx = c * 256 + tid;
      int r = idx >> 7, col = idx & 127;
      xch[r * 128 + col] = x[(size_t)(m0 + r) * 512 + k0 + col];
    }
    __syncthreads();
    for (int k = 0; k < 128; k += 4) {
      float w0 = wch[(k + 0) * 64 + j];
      float w1 = wch[(k + 1) * 64 + j];
      float w2v = wch[(k + 2) * 64 + j];
      float w3v = wch[(k + 3) * 64 + j];
      #pragma unroll
      for (int si = 0; si < 4; ++si) {
        const float4 xv = *(const float4*)&xch[(sub * 4 + si) * 128 + k];
        acc[si] = fmaf(xv.x, w0, acc[si]);
        acc[si] = fmaf(xv.y, w1, acc[si]);
        acc[si] = fmaf(xv.z, w2v, acc[si]);
        acc[si] = fmaf(xv.w, w3v, acc[si]);
      }
    }
  }
  float bj = b1[j];
  #pragma unroll
  for (int si = 0; si < 4; ++si) {
    int s = sub * 4 + si;
    float h = acc[si] + bj;
    h = h > 0.f ? h : 0.f;
    H1[(size_t)(m0 + s) * 64 + j] = h;
    h1s[s * 64 + j] = h;
  }
  __syncthreads();
  float acc2[4] = {0.f, 0.f, 0.f, 0.f};
  for (int k = 0; k < 64; k += 4) {
    float w0 = W2s[(k + 0) * 64 + j];
    float w1 = W2s[(k + 1) * 64 + j];
    float w2v = W2s[(k + 2) * 64 + j];
    float w3v = W2s[(k + 3) * 64 + j];
    #pragma unroll
    for (int si = 0; si < 4; ++si) {
      const float4 hv = *(const float4*)&h1s[(sub * 4 + si) * 64 + k];
      acc2[si] = fmaf(hv.x, w0, acc2[si]);
      acc2[si] = fmaf(hv.y, w1, acc2[si]);
      acc2[si] = fmaf(hv.z, w2v, acc2[si]);
      acc2[si] = fmaf(hv.w, w3v, acc2[si]);
    }
  }
  float b2j = b2[j];
  #pragma unroll
  for (int si = 0; si < 4; ++si) {
    int s = sub * 4 + si;
    float h = acc2[si] + b2j;
    h = h > 0.f ? h : 0.f;
    H2[(size_t)(m0 + s) * 64 + j] = h;
  }
}

// ---------------------------------------------------------------------------
// K2: F = H2 W3 + b3   [B,512]
// block: 256 thr; 16 samples x 128 cols; K=64
__global__ __launch_bounds__(256) void k_f(
    const float* __restrict__ H2, const float* __restrict__ W3, const float* __restrict__ b3,
    float* __restrict__ F) {
  __shared__ float W3c[64 * 128];  // [k][n_local]
  __shared__ float h2s[16 * 64];   // [s][k]
  const int tid = threadIdx.x;
  const int j = tid & 127, sub = tid >> 7;
  const int m0 = (blockIdx.x >> 2) * 16;
  const int n0 = (blockIdx.x & 3) * 128;

  #pragma unroll
  for (int c = 0; c < 32; ++c) {
    int idx = c * 256 + tid;
    int k = idx >> 7, col = idx & 127;
    W3c[idx] = W3[(size_t)k * 512 + n0 + col];
  }
  #pragma unroll
  for (int c = 0; c < 4; ++c) {
    int idx = c * 256 + tid;
    int r = idx >> 6, k = idx & 63;
    h2s[idx] = H2[(size_t)(m0 + r) * 64 + k];
  }
  __syncthreads();
  float acc[8] = {0.f, 0.f, 0.f, 0.f, 0.f, 0.f, 0.f, 0.f};
  for (int k = 0; k < 64; k += 4) {
    float w0 = W3c[(k + 0) * 128 + j];
    float w1 = W3c[(k + 1) * 128 + j];
    float w2v = W3c[(k + 2) * 128 + j];
    float w3v = W3c[(k + 3) * 128 + j];
    #pragma unroll
    for (int si = 0; si < 8; ++si) {
      const float4 hv = *(const float4*)&h2s[(sub * 8 + si) * 64 + k];
      acc[si] = fmaf(hv.x, w0, acc[si]);
      acc[si] = fmaf(hv.y, w1, acc[si]);
      acc[si] = fmaf(hv.z, w2v, acc[si]);
      acc[si] = fmaf(hv.w, w3v, acc[si]);
    }
  }
  float bv = b3[n0 + j];
  #pragma unroll
  for (int si = 0; si < 8; ++si) {
    int s = sub * 8 + si;
    F[(size_t)(m0 + s) * 512 + n0 + j] = acc[si] + bv;
  }
}

// ---------------------------------------------------------------------------
// K3: G1 = relu(F V1 + c1)  [B,64]
__global__ __launch_bounds__(256) void k_g1(
    const float* __restrict__ F, const float* __restrict__ V1, const float* __restrict__ c1,
    float* __restrict__ G1) {
  __shared__ float wch[128 * 64];  // V1 chunk, [k][j]
  __shared__ float fch[16 * 128];  // [s][k]
  const int tid = threadIdx.x;
  const int j = tid & 63, sub = tid >> 6;
  const int m0 = blockIdx.x * 16;

  float acc[4] = {0.f, 0.f, 0.f, 0.f};
  for (int k0 = 0; k0 < 512; k0 += 128) {
    __syncthreads();
    #pragma unroll
    for (int c = 0; c < 32; ++c) wch[c * 256 + tid] = V1[(size_t)k0 * 64 + c * 256 + tid];
    #pragma unroll
    for (int c = 0; c < 8; ++c) {
      int idx = c * 256 + tid;
      int r = idx >> 7, col = idx & 127;
      fch[r * 128 + col] = F[(size_t)(m0 + r) * 512 + k0 + col];
    }
    __syncthreads();
    for (int k = 0; k < 128; k += 4) {
      float w0 = wch[(k + 0) * 64 + j];
      float w1 = wch[(k + 1) * 64 + j];
      float w2v = wch[(k + 2) * 64 + j];
      float w3v = wch[(k + 3) * 64 + j];
      #pragma unroll
      for (int si = 0; si < 4; ++si) {
        const float4 xv = *(const float4*)&fch[(sub * 4 + si) * 128 + k];
        acc[si] = fmaf(xv.x, w0, acc[si]);
        acc[si] = fmaf(xv.y, w1, acc[si]);
        acc[si] = fmaf(xv.z, w2v, acc[si]);
        acc[si] = fmaf(xv.w, w3v, acc[si]);
      }
    }
  }
  float cj = c1[j];
  #pragma unroll
  for (int si = 0; si < 4; ++si) {
    int s = sub * 4 + si;
    float g = acc[si] + cj;
    g = g > 0.f ? g : 0.f;
    G1[(size_t)(m0 + s) * 64 + j] = g;
  }
}

// ---------------------------------------------------------------------------
// K4: per-sample (wave per sample): g2pre, lyap, s2
__global__ __launch_bounds__(256) void k_small(
    const float* __restrict__ G1, const float* __restrict__ F,
    const float* __restrict__ V2, const float* __restrict__ c2,
    const float* __restrict__ V3, const float* __restrict__ c3,
    float* __restrict__ s2out, float* __restrict__ lyap) {
  __shared__ float V2s[64 * 64];   // natural [k][j]
  __shared__ float V2T[64 * 65];   // V2T[b*65+a] = V2[a][b]
  __shared__ float g1s[4 * 64];
  __shared__ float s3s[4 * 64];
  const int tid = threadIdx.x;
  const int j = tid & 63, w = tid >> 6;
  const size_t i = (size_t)blockIdx.x * 4 + w;

  #pragma unroll
  for (int c = 0; c < 16; ++c) {
    int idx = c * 256 + tid;
    float v = V2[idx];
    V2s[idx] = v;
    int a = idx >> 6, b = idx & 63;
    V2T[b * 65 + a] = v;
  }
  float g1v = G1[i * 64 + j];
  g1s[w * 64 + j] = g1v;
  __syncthreads();

  float g2pre = c2[j];
  for (int k = 0; k < 64; ++k) g2pre = fmaf(g1s[w * 64 + k], V2s[k * 64 + j], g2pre);
  float g2 = g2pre > 0.f ? g2pre : 0.f;
  float v3j = V3[j];
  float s3 = g2pre > 0.f ? v3j : 0.f;
  s3s[w * 64 + j] = s3;
  __syncthreads();

  float s2v = 0.f;
  for (int k = 0; k < 64; ++k) s2v = fmaf(s3s[w * 64 + k], V2T[k * 65 + j], s2v);
  s2v = g1v > 0.f ? s2v : 0.f;
  s2out[i * 64 + j] = s2v;

  // lyap = sum_j g2*V3 + c3 + EPS * ||F_row||^2
  const float4* f4p = (const float4*)(F + i * 512);
  float ss = 0.f;
  #pragma unroll
  for (int c = 0; c < 2; ++c) {
    float4 fv = f4p[j + 64 * c];
    ss += fv.x * fv.x + fv.y * fv.y + fv.z * fv.z + fv.w * fv.w;
  }
  float val = g2 * v3j + EPS_C * ss;
  #pragma unroll
  for (int off = 32; off; off >>= 1) val += __shfl_xor(val, off);
  if (j == 0) lyap[i] = val + c3[0];
}

// ---------------------------------------------------------------------------
// K5: U = s2 V1^T + 2*EPS*F   [B,512]
__global__ __launch_bounds__(256) void k_u(
    const float* __restrict__ s2, const float* __restrict__ V1, const float* __restrict__ F,
    float* __restrict__ U) {
  __shared__ float V1Tc[64 * 129]; // V1Tc[k*129+n_l] = V1[(n0+n_l)*64+k]
  __shared__ float s2s[16 * 64];
  const int tid = threadIdx.x;
  const int j = tid & 127, sub = tid >> 7;
  const int m0 = (blockIdx.x >> 2) * 16;
  const int n0 = (blockIdx.x & 3) * 128;

  #pragma unroll
  for (int c = 0; c < 32; ++c) {
    int idx = c * 256 + tid;
    int nl = idx >> 6, k = idx & 63;
    V1Tc[k * 129 + nl] = V1[(size_t)n0 * 64 + idx];
  }
  #pragma unroll
  for (int c = 0; c < 4; ++c) {
    int idx = c * 256 + tid;
    int r = idx >> 6, k = idx & 63;
    s2s[idx] = s2[(size_t)(m0 + r) * 64 + k];
  }
  __syncthreads();
  float acc[8] = {0.f, 0.f, 0.f, 0.f, 0.f, 0.f, 0.f, 0.f};
  for (int k = 0; k < 64; k += 4) {
    float w0 = V1Tc[(k + 0) * 129 + j];
    float w1 = V1Tc[(k + 1) * 129 + j];
    float w2v = V1Tc[(k + 2) * 129 + j];
    float w3v = V1Tc[(k + 3) * 129 + j];
    #pragma unroll
    for (int si = 0; si < 8; ++si) {
      const float4 sv = *(const float4*)&s2s[(sub * 8 + si) * 64 + k];
      acc[si] = fmaf(sv.x, w0, acc[si]);
      acc[si] = fmaf(sv.y, w1, acc[si]);
      acc[si] = fmaf(sv.z, w2v, acc[si]);
      acc[si] = fmaf(sv.w, w3v, acc[si]);
    }
  }
  #pragma unroll
  for (int si = 0; si < 8; ++si) {
    int s = sub * 8 + si;
    size_t idx = (size_t)(m0 + s) * 512 + n0 + j;
    U[idx] = acc[si] + 2.f * EPS_C * F[idx];
  }
}

// ---------------------------------------------------------------------------
// K6: T3 = (U W3^T) .* (H2>0);  T2 = (T3 W2^T) .* (H1>0)   [B,64]
__global__ __launch_bounds__(256) void k_t(
    const float* __restrict__ U, const float* __restrict__ W3, const float* __restrict__ W2,
    const float* __restrict__ H1, const float* __restrict__ H2, float* __restrict__ T2) {
  __shared__ float W3Tc[128 * 65]; // W3Tc[n*65+jr] = W3[jr][n0+n]
  __shared__ float uch[16 * 128];
  __shared__ float W2Tl[64 * 65];  // W2Tl[b*65+a] = W2[a][b]
  __shared__ float t3s[16 * 64];
  const int tid = threadIdx.x;
  const int j = tid & 63, sub = tid >> 6;
  const int m0 = blockIdx.x * 16;

  #pragma unroll
  for (int c = 0; c < 16; ++c) {
    int idx = c * 256 + tid;
    int a = idx >> 6, b = idx & 63;
    W2Tl[b * 65 + a] = W2[idx];
  }
  float acc[4] = {0.f, 0.f, 0.f, 0.f};
  for (int n0 = 0; n0 < 512; n0 += 128) {
    __syncthreads();
    #pragma unroll
    for (int c = 0; c < 32; ++c) {
      int idx = c * 256 + tid;
      int jr = idx >> 7, col = idx & 127;
      W3Tc[col * 65 + jr] = W3[(size_t)jr * 512 + n0 + col];
    }
    #pragma unroll
    for (int c = 0; c < 8; ++c) {
      int idx = c * 256 + tid;
      int r = idx >> 7, col = idx & 127;
      uch[r * 128 + col] = U[(size_t)(m0 + r) * 512 + n0 + col];
    }
    __syncthreads();
    for (int n = 0; n < 128; n += 4) {
      float w0 = W3Tc[(n + 0) * 65 + j];
      float w1 = W3Tc[(n + 1) * 65 + j];
      float w2v = W3Tc[(n + 2) * 65 + j];
      float w3v = W3Tc[(n + 3) * 65 + j];
      #pragma unroll
      for (int si = 0; si < 4; ++si) {
        const float4 uv = *(const float4*)&uch[(sub * 4 + si) * 128 + n];
        acc[si] = fmaf(uv.x, w0, acc[si]);
        acc[si] = fmaf(uv.y, w1, acc[si]);
        acc[si] = fmaf(uv.z, w2v, acc[si]);
        acc[si] = fmaf(uv.w, w3v, acc[si]);
      }
    }
  }
  #pragma unroll
  for (int si = 0; si < 4; ++si) {
    int s = sub * 4 + si;
    float h2v = H2[(size_t)(m0 + s) * 64 + j];
    t3s[s * 64 + j] = h2v > 0.f ? acc[si] : 0.f;
  }
  __syncthreads();
  float acc2[4] = {0.f, 0.f, 0.f, 0.f};
  for (int jj = 0; jj < 64; ++jj) {
    float wv = W2Tl[jj * 65 + j];
    #pragma unroll
    for (int si = 0; si < 4; ++si)
      acc2[si] = fmaf(t3s[(sub * 4 + si) * 64 + jj], wv, acc2[si]);
  }
  #pragma unroll
  for (int si = 0; si < 4; ++si) {
    int s = sub * 4 + si;
    float h1v = H1[(size_t)(m0 + s) * 64 + j];
    T2[(size_t)(m0 + s) * 64 + j] = h1v > 0.f ? acc2[si] : 0.f;
  }
}

// ---------------------------------------------------------------------------
// K7: GV = T2 W1^T   [B,512]
__global__ __launch_bounds__(256) void k_gv(
    const float* __restrict__ T2, const float* __restrict__ W1, float* __restrict__ GV) {
  __shared__ float W1Tc[64 * 129]; // [k*129+n_l] = W1[(n0+n_l)*64+k]
  __shared__ float t2s[16 * 64];
  const int tid = threadIdx.x;
  const int j = tid & 127, sub = tid >> 7;
  const int m0 = (blockIdx.x >> 2) * 16;
  const int n0 = (blockIdx.x & 3) * 128;

  #pragma unroll
  for (int c = 0; c < 32; ++c) {
    int idx = c * 256 + tid;
    int nl = idx >> 6, k = idx & 63;
    W1Tc[k * 129 + nl] = W1[(size_t)n0 * 64 + idx];
  }
  #pragma unroll
  for (int c = 0; c < 4; ++c) {
    int idx = c * 256 + tid;
    int r = idx >> 6, k = idx & 63;
    t2s[idx] = T2[(size_t)(m0 + r) * 64 + k];
  }
  __syncthreads();
  float acc[8] = {0.f, 0.f, 0.f, 0.f, 0.f, 0.f, 0.f, 0.f};
  for (int k = 0; k < 64; k += 4) {
    float w0 = W1Tc[(k + 0) * 129 + j];
    float w1 = W1Tc[(k + 1) * 129 + j];
    float w2v = W1Tc[(k + 2) * 129 + j];
    float w3v = W1Tc[(k + 3) * 129 + j];
    #pragma unroll
    for (int si = 0; si < 8; ++si) {
      const float4 tv = *(const float4*)&t2s[(sub * 8 + si) * 64 + k];
      acc[si] = fmaf(tv.x, w0, acc[si]);
      acc[si] = fmaf(tv.y, w1, acc[si]);
      acc[si] = fmaf(tv.z, w2v, acc[si]);
      acc[si] = fmaf(tv.w, w3v, acc[si]);
    }
  }
  #pragma unroll
  for (int si = 0; si < 8; ++si) {
    int s = sub * 8 + si;
    GV[(size_t)(m0 + s) * 512 + n0 + j] = acc[si];
  }
}

// ---------------------------------------------------------------------------
// K8: dot_i, num_i = relu(dot + alpha*lyap); partial denom atomics
__global__ __launch_bounds__(256) void k_dot(
    const float* __restrict__ GV, const float* __restrict__ lyap,
    float* __restrict__ num, float* __restrict__ dparts) {
  __shared__ float dsum[4];
  const int tid = threadIdx.x;
  const int j = tid & 63, w = tid >> 6;
  const size_t i = (size_t)blockIdx.x * 4 + w;
  const float4* g4 = (const float4*)(GV + i * 512);
  float ss = 0.f;
  #pragma unroll
  for (int c = 0; c < 2; ++c) {
    float4 g = g4[j + 64 * c];
    ss += g.x * g.x + g.y * g.y + g.z * g.z + g.w * g.w;
  }
  #pragma unroll
  for (int off = 32; off; off >>= 1) ss += __shfl_xor(ss, off);
  if (j == 0) {
    float nm = ss + ALPHA_C * lyap[i];
    num[i] = nm > 0.f ? nm : 0.f;
    dsum[w] = ss;
  }
  __syncthreads();
  if (tid == 0) {
    atomicAdd(&dparts[blockIdx.x & 255], dsum[0] + dsum[1] + dsum[2] + dsum[3]);
  }
}

// ---------------------------------------------------------------------------
// K9: out = F - (num_i/denom) * GV
__global__ __launch_bounds__(256) void k_out(
    const float* __restrict__ F, const float* __restrict__ GV,
    const float* __restrict__ num, const float* __restrict__ dparts,
    float* __restrict__ out) {
  __shared__ float red[256];
  const int tid = threadIdx.x;
  red[tid] = dparts[tid];
  __syncthreads();
  for (int s = 128; s >= 1; s >>= 1) {
    if (tid < s) red[tid] += red[tid + s];
    __syncthreads();
  }
  const float denom = red[0];
  const size_t base = (size_t)blockIdx.x * 2048;
  #pragma unroll
  for (int c = 0; c < 2; ++c) {
    size_t idx = base + (size_t)c * 1024 + (size_t)tid * 4;
    size_t i = idx >> 9;
    float sc = num[i] / denom;
    float4 fv = *(const float4*)(F + idx);
    float4 gv = *(const float4*)(GV + idx);
    float4 o;
    o.x = fv.x - sc * gv.x;
    o.y = fv.y - sc * gv.y;
    o.z = fv.z - sc * gv.z;
    o.w = fv.w - sc * gv.w;
    *(float4*)(out + idx) = o;
  }
}

// ---------------------------------------------------------------------------
extern "C" void kernel_launch(void* const* d_in, const int* in_sizes, int n_in,
                              void* d_out, int out_size, void* d_ws, size_t ws_size,
                              hipStream_t stream) {
  const float* x  = (const float*)d_in[0];
  const float* W1 = (const float*)d_in[1];
  const float* b1 = (const float*)d_in[2];
  const float* W2 = (const float*)d_in[3];
  const float* b2 = (const float*)d_in[4];
  const float* W3 = (const float*)d_in[5];
  const float* b3 = (const float*)d_in[6];
  const float* V1 = (const float*)d_in[7];
  const float* c1 = (const float*)d_in[8];
  const float* V2 = (const float*)d_in[9];
  const float* c2 = (const float*)d_in[10];
  const float* V3 = (const float*)d_in[11];
  const float* c3 = (const float*)d_in[12];
  float* out = (float*)d_out;

  float* ws = (float*)d_ws;
  float* F    = ws + OFF_F;
  float* GVU  = ws + OFF_GVU;   // holds U, then GV
  float* H1   = ws + OFF_H1;
  float* H2   = ws + OFF_H2;
  float* G1T2 = ws + OFF_G1T2;  // holds G1, then T2
  float* S2   = ws + OFF_S2;
  float* LY   = ws + OFF_LYAP;
  float* NUM  = ws + OFF_NUM;
  float* DP   = ws + OFF_DPART;

  hipMemsetAsync(DP, 0, 256 * sizeof(float), stream);

  k_h12<<<2048, 256, 0, stream>>>(x, W1, b1, W2, b2, H1, H2);
  k_f<<<8192, 256, 0, stream>>>(H2, W3, b3, F);
  k_g1<<<2048, 256, 0, stream>>>(F, V1, c1, G1T2);
  k_small<<<8192, 256, 0, stream>>>(G1T2, F, V2, c2, V3, c3, S2, LY);
  k_u<<<8192, 256, 0, stream>>>(S2, V1, F, GVU);
  k_t<<<2048, 256, 0, stream>>>(GVU, W3, W2, H1, H2, G1T2);   // T2 overwrites G1
  k_gv<<<8192, 256, 0, stream>>>(G1T2, W1, GVU);              // GV overwrites U
  k_dot<<<8192, 256, 0, stream>>>(GVU, LY, NUM, DP);
  k_out<<<8192, 256, 0, stream>>>(F, GVU, NUM, DP, out);
}

// Round 2
// 278.936 us; speedup vs baseline: 3.3427x; 3.3427x over previous
//
#include <hip/hip_runtime.h>

#define ALPHA_C 0.9f
#define EPS_C 1e-3f

typedef unsigned short u16;
typedef __attribute__((ext_vector_type(8))) short short8;
typedef __attribute__((ext_vector_type(4))) float f32x4;
#define MFMA(a, b, c) __builtin_amdgcn_mfma_f32_16x16x32_bf16(a, b, c, 0, 0, 0)

__device__ __forceinline__ u16 f2bf(float f) {
  union { float f; unsigned u; } v; v.f = f;
  unsigned u = v.u;
  u += 0x7FFFu + ((u >> 16) & 1u);
  return (u16)(u >> 16);
}
__device__ __forceinline__ float bf2f(u16 h) {
  union { unsigned u; float f; } v; v.u = ((unsigned)h) << 16;
  return v.f;
}

// ---------------------------------------------------------------------------
// K0: weight conversion fp32 -> bf16 (natural + transposed copies)
__global__ __launch_bounds__(256) void k_conv(
    const float* __restrict__ W1, const float* __restrict__ W2, const float* __restrict__ W3,
    const float* __restrict__ V1,
    u16* __restrict__ W1T, u16* __restrict__ W1n, u16* __restrict__ W2T, u16* __restrict__ W2n,
    u16* __restrict__ W3T, u16* __restrict__ W3n, u16* __restrict__ V1T, u16* __restrict__ V1n) {
  int i = blockIdx.x * 256 + threadIdx.x;   // 0..32767
  { float v = W1[i]; int k = i >> 6, j = i & 63; u16 b = f2bf(v); W1n[i] = b; W1T[j * 512 + k] = b; }
  { float v = V1[i]; int k = i >> 6, j = i & 63; u16 b = f2bf(v); V1n[i] = b; V1T[j * 512 + k] = b; }
  { float v = W3[i]; int k = i >> 9, n = i & 511; u16 b = f2bf(v); W3n[i] = b; W3T[n * 64 + k] = b; }
  if (i < 4096) { float v = W2[i]; int k = i >> 6, j = i & 63; u16 b = f2bf(v); W2n[i] = b; W2T[j * 64 + k] = b; }
}

// ---------------------------------------------------------------------------
// K1: H1 = relu(x W1 + b1), H2 = relu(H1 W2 + b2)  -> bf16 [B,64] each
// 512 blocks x 256 thr; 64 samples/block; MFMA 16x16x32
__global__ __launch_bounds__(256) void k_h12(
    const float* __restrict__ x, const u16* __restrict__ W1T, const float* __restrict__ b1,
    const u16* __restrict__ W2T, const float* __restrict__ b2,
    u16* __restrict__ H1b, u16* __restrict__ H2b) {
  __shared__ u16 As[64 * 136];
  __shared__ u16 Bs[64 * 136];
  __shared__ u16 W2s[64 * 72];
  __shared__ u16 Hs[64 * 72];
  const int tid = threadIdx.x;
  const int lane = tid & 63, w = tid >> 6, q = lane >> 4, r = lane & 15;
  const int m0 = blockIdx.x * 64;

  #pragma unroll
  for (int c = 0; c < 2; ++c) {
    int idx = c * 256 + tid; int a = idx >> 3, k8 = (idx & 7) * 8;
    *(short8*)&W2s[a * 72 + k8] = *(const short8*)&W2T[a * 64 + k8];
  }

  f32x4 acc[4] = {};
  for (int kc = 0; kc < 4; ++kc) {
    __syncthreads();
    #pragma unroll
    for (int c = 0; c < 8; ++c) {
      int idx = c * 256 + tid; int rr = idx >> 5, k4 = (idx & 31) * 4;
      float4 v = *(const float4*)&x[(size_t)(m0 + rr) * 512 + kc * 128 + k4];
      As[rr * 136 + k4 + 0] = f2bf(v.x);
      As[rr * 136 + k4 + 1] = f2bf(v.y);
      As[rr * 136 + k4 + 2] = f2bf(v.z);
      As[rr * 136 + k4 + 3] = f2bf(v.w);
    }
    #pragma unroll
    for (int c = 0; c < 4; ++c) {
      int idx = c * 256 + tid; int rr = idx >> 4, k8 = (idx & 15) * 8;
      *(short8*)&Bs[rr * 136 + k8] = *(const short8*)&W1T[rr * 512 + kc * 128 + k8];
    }
    __syncthreads();
    #pragma unroll
    for (int ks = 0; ks < 4; ++ks) {
      short8 a = *(const short8*)&As[(w * 16 + r) * 136 + ks * 32 + q * 8];
      #pragma unroll
      for (int t = 0; t < 4; ++t) {
        short8 b = *(const short8*)&Bs[(t * 16 + r) * 136 + ks * 32 + q * 8];
        acc[t] = MFMA(a, b, acc[t]);
      }
    }
  }
  __syncthreads();
  #pragma unroll
  for (int t = 0; t < 4; ++t) {
    int col = t * 16 + r; float bv = b1[col];
    #pragma unroll
    for (int g = 0; g < 4; ++g) {
      float h = acc[t][g] + bv; h = h > 0.f ? h : 0.f;
      Hs[(w * 16 + q * 4 + g) * 72 + col] = f2bf(h);
    }
  }
  __syncthreads();
  #pragma unroll
  for (int c = 0; c < 2; ++c) {
    int idx = c * 256 + tid; int rr = idx >> 3, k8 = (idx & 7) * 8;
    *(short8*)&H1b[(size_t)(m0 + rr) * 64 + k8] = *(const short8*)&Hs[rr * 72 + k8];
  }
  f32x4 acc2[4] = {};
  #pragma unroll
  for (int ks = 0; ks < 2; ++ks) {
    short8 a = *(const short8*)&Hs[(w * 16 + r) * 72 + ks * 32 + q * 8];
    #pragma unroll
    for (int t = 0; t < 4; ++t) {
      short8 b = *(const short8*)&W2s[(t * 16 + r) * 72 + ks * 32 + q * 8];
      acc2[t] = MFMA(a, b, acc2[t]);
    }
  }
  __syncthreads();
  #pragma unroll
  for (int t = 0; t < 4; ++t) {
    int col = t * 16 + r; float bv = b2[col];
    #pragma unroll
    for (int g = 0; g < 4; ++g) {
      float h = acc2[t][g] + bv; h = h > 0.f ? h : 0.f;
      Hs[(w * 16 + q * 4 + g) * 72 + col] = f2bf(h);
    }
  }
  __syncthreads();
  #pragma unroll
  for (int c = 0; c < 2; ++c) {
    int idx = c * 256 + tid; int rr = idx >> 3, k8 = (idx & 7) * 8;
    *(short8*)&H2b[(size_t)(m0 + rr) * 64 + k8] = *(const short8*)&Hs[rr * 72 + k8];
  }
}

// ---------------------------------------------------------------------------
// K2: F = H2 W3 + b3 (fp32 [B,512]); G1 = relu(F V1 + c1) bf16 [B,64]; SUMF2[i]=||F_i||^2
__global__ __launch_bounds__(256) void k_fg1(
    const u16* __restrict__ H2b, const u16* __restrict__ W3T, const float* __restrict__ b3,
    const u16* __restrict__ V1T, const float* __restrict__ c1,
    float* __restrict__ F, u16* __restrict__ G1b, float* __restrict__ SUMF2) {
  __shared__ u16 H2s[64 * 72];
  __shared__ u16 Bs[128 * 72];   // also viewed as [64][136]
  __shared__ u16 Fb[64 * 136];
  const int tid = threadIdx.x;
  const int lane = tid & 63, w = tid >> 6, q = lane >> 4, r = lane & 15;
  const int m0 = blockIdx.x * 64;

  #pragma unroll
  for (int c = 0; c < 2; ++c) {
    int idx = c * 256 + tid; int a = idx >> 3, k8 = (idx & 7) * 8;
    *(short8*)&H2s[a * 72 + k8] = *(const short8*)&H2b[(size_t)(m0 + a) * 64 + k8];
  }
  f32x4 g1acc[4] = {};
  float ssq[4] = {0.f, 0.f, 0.f, 0.f};
  for (int nc = 0; nc < 4; ++nc) {
    __syncthreads();
    #pragma unroll
    for (int c = 0; c < 4; ++c) {
      int idx = c * 256 + tid; int nl = idx >> 3, k8 = (idx & 7) * 8;
      *(short8*)&Bs[nl * 72 + k8] = *(const short8*)&W3T[(size_t)(nc * 128 + nl) * 64 + k8];
    }
    __syncthreads();
    f32x4 facc[8] = {};
    #pragma unroll
    for (int ks = 0; ks < 2; ++ks) {
      short8 a = *(const short8*)&H2s[(w * 16 + r) * 72 + ks * 32 + q * 8];
      #pragma unroll
      for (int t = 0; t < 8; ++t) {
        short8 b = *(const short8*)&Bs[(t * 16 + r) * 72 + ks * 32 + q * 8];
        facc[t] = MFMA(a, b, facc[t]);
      }
    }
    #pragma unroll
    for (int t = 0; t < 8; ++t) {
      int colg = nc * 128 + t * 16 + r;
      float bv = b3[colg];
      #pragma unroll
      for (int g = 0; g < 4; ++g) {
        float v = facc[t][g] + bv;
        int rl = w * 16 + q * 4 + g;
        F[(size_t)(m0 + rl) * 512 + colg] = v;
        ssq[g] += v * v;
        Fb[rl * 136 + t * 16 + r] = f2bf(v);
      }
    }
    __syncthreads();
    #pragma unroll
    for (int c = 0; c < 4; ++c) {
      int idx = c * 256 + tid; int jj = idx >> 4, k8 = (idx & 15) * 8;
      *(short8*)&Bs[jj * 136 + k8] = *(const short8*)&V1T[(size_t)jj * 512 + nc * 128 + k8];
    }
    __syncthreads();
    #pragma unroll
    for (int ks = 0; ks < 4; ++ks) {
      short8 a = *(const short8*)&Fb[(w * 16 + r) * 136 + ks * 32 + q * 8];
      #pragma unroll
      for (int t = 0; t < 4; ++t) {
        short8 b = *(const short8*)&Bs[(t * 16 + r) * 136 + ks * 32 + q * 8];
        g1acc[t] = MFMA(a, b, g1acc[t]);
      }
    }
  }
  #pragma unroll
  for (int t = 0; t < 4; ++t) {
    int col = t * 16 + r; float cv = c1[col];
    #pragma unroll
    for (int g = 0; g < 4; ++g) {
      float v = g1acc[t][g] + cv; v = v > 0.f ? v : 0.f;
      G1b[(size_t)(m0 + w * 16 + q * 4 + g) * 64 + col] = f2bf(v);
    }
  }
  #pragma unroll
  for (int g = 0; g < 4; ++g) {
    float s = ssq[g];
    s += __shfl_xor(s, 1); s += __shfl_xor(s, 2); s += __shfl_xor(s, 4); s += __shfl_xor(s, 8);
    if (r == 0) SUMF2[m0 + w * 16 + q * 4 + g] = s;
  }
}

// ---------------------------------------------------------------------------
// K3: per-sample small net: g2, s2 (bf16), lyap
__global__ __launch_bounds__(256) void k_small(
    const u16* __restrict__ G1b, const float* __restrict__ V2, const float* __restrict__ c2,
    const float* __restrict__ V3, const float* __restrict__ c3, const float* __restrict__ SUMF2,
    u16* __restrict__ S2b, float* __restrict__ LYAP) {
  __shared__ float V2s[64 * 64];
  __shared__ float V2T[64 * 65];
  const int tid = threadIdx.x; const int j = tid & 63, w = tid >> 6;
  #pragma unroll
  for (int c = 0; c < 16; ++c) {
    int idx = c * 256 + tid; float v = V2[idx];
    V2s[idx] = v; V2T[(idx & 63) * 65 + (idx >> 6)] = v;
  }
  __syncthreads();
  const float v3j = V3[j], c2j = c2[j], c3v = c3[0];
  const int base = blockIdx.x * 64 + w * 16;
  for (int s = 0; s < 16; ++s) {
    size_t i = (size_t)(base + s);
    float g1v = bf2f(G1b[i * 64 + j]);
    float g2pre = c2j;
    for (int k = 0; k < 64; ++k) g2pre = fmaf(__shfl(g1v, k), V2s[k * 64 + j], g2pre);
    float g2 = g2pre > 0.f ? g2pre : 0.f;
    float s3 = g2pre > 0.f ? v3j : 0.f;
    float s2v = 0.f;
    for (int k = 0; k < 64; ++k) s2v = fmaf(__shfl(s3, k), V2T[k * 65 + j], s2v);
    s2v = g1v > 0.f ? s2v : 0.f;
    S2b[i * 64 + j] = f2bf(s2v);
    float val = g2 * v3j;
    #pragma unroll
    for (int off = 32; off; off >>= 1) val += __shfl_xor(val, off);
    if (j == 0) LYAP[i] = val + c3v + EPS_C * SUMF2[i];
  }
}

// ---------------------------------------------------------------------------
// K4: U = s2 V1^T + 2eps*F ; T3 = (U W3^T)*(H2>0) ; T2 = (T3 W2^T)*(H1>0)  -> bf16 [B,64]
__global__ __launch_bounds__(256) void k_ut(
    const u16* __restrict__ S2b, const u16* __restrict__ V1n, const float* __restrict__ F,
    const u16* __restrict__ W3n, const u16* __restrict__ W2n,
    const u16* __restrict__ H1b, const u16* __restrict__ H2b,
    u16* __restrict__ T2b) {
  __shared__ u16 S2s[64 * 72];
  __shared__ u16 Bs[128 * 72];
  __shared__ u16 Ub[64 * 136];
  __shared__ u16 W2s[64 * 72];
  __shared__ u16 T3s[64 * 72];
  const int tid = threadIdx.x;
  const int lane = tid & 63, w = tid >> 6, q = lane >> 4, r = lane & 15;
  const int m0 = blockIdx.x * 64;

  #pragma unroll
  for (int c = 0; c < 2; ++c) {
    int idx = c * 256 + tid; int a = idx >> 3, k8 = (idx & 7) * 8;
    *(short8*)&S2s[a * 72 + k8] = *(const short8*)&S2b[(size_t)(m0 + a) * 64 + k8];
    *(short8*)&W2s[a * 72 + k8] = *(const short8*)&W2n[a * 64 + k8];
  }
  f32x4 t3acc[4] = {};
  for (int nc = 0; nc < 4; ++nc) {
    __syncthreads();
    #pragma unroll
    for (int c = 0; c < 4; ++c) {
      int idx = c * 256 + tid; int nl = idx >> 3, k8 = (idx & 7) * 8;
      *(short8*)&Bs[nl * 72 + k8] = *(const short8*)&V1n[(size_t)(nc * 128 + nl) * 64 + k8];
    }
    __syncthreads();
    f32x4 uacc[8] = {};
    #pragma unroll
    for (int ks = 0; ks < 2; ++ks) {
      short8 a = *(const short8*)&S2s[(w * 16 + r) * 72 + ks * 32 + q * 8];
      #pragma unroll
      for (int t = 0; t < 8; ++t) {
        short8 b = *(const short8*)&Bs[(t * 16 + r) * 72 + ks * 32 + q * 8];
        uacc[t] = MFMA(a, b, uacc[t]);
      }
    }
    #pragma unroll
    for (int t = 0; t < 8; ++t) {
      int colg = nc * 128 + t * 16 + r;
      #pragma unroll
      for (int g = 0; g < 4; ++g) {
        int rl = w * 16 + q * 4 + g;
        float u = uacc[t][g] + 2.f * EPS_C * F[(size_t)(m0 + rl) * 512 + colg];
        Ub[rl * 136 + t * 16 + r] = f2bf(u);
      }
    }
    __syncthreads();
    #pragma unroll
    for (int c = 0; c < 4; ++c) {
      int idx = c * 256 + tid; int jj = idx >> 4, k8 = (idx & 15) * 8;
      *(short8*)&Bs[jj * 136 + k8] = *(const short8*)&W3n[(size_t)jj * 512 + nc * 128 + k8];
    }
    __syncthreads();
    #pragma unroll
    for (int ks = 0; ks < 4; ++ks) {
      short8 a = *(const short8*)&Ub[(w * 16 + r) * 136 + ks * 32 + q * 8];
      #pragma unroll
      for (int t = 0; t < 4; ++t) {
        short8 b = *(const short8*)&Bs[(t * 16 + r) * 136 + ks * 32 + q * 8];
        t3acc[t] = MFMA(a, b, t3acc[t]);
      }
    }
  }
  #pragma unroll
  for (int t = 0; t < 4; ++t) {
    int col = t * 16 + r;
    #pragma unroll
    for (int g = 0; g < 4; ++g) {
      int rl = w * 16 + q * 4 + g;
      u16 h2u = H2b[(size_t)(m0 + rl) * 64 + col];
      float v = h2u ? t3acc[t][g] : 0.f;
      T3s[rl * 72 + col] = f2bf(v);
    }
  }
  f32x4 t2acc[4] = {};
  #pragma unroll
  for (int ks = 0; ks < 2; ++ks) {
    short8 a = *(const short8*)&T3s[(w * 16 + r) * 72 + ks * 32 + q * 8];
    #pragma unroll
    for (int t = 0; t < 4; ++t) {
      short8 b = *(const short8*)&W2s[(t * 16 + r) * 72 + ks * 32 + q * 8];
      t2acc[t] = MFMA(a, b, t2acc[t]);
    }
  }
  #pragma unroll
  for (int t = 0; t < 4; ++t) {
    int col = t * 16 + r;
    #pragma unroll
    for (int g = 0; g < 4; ++g) {
      int rl = w * 16 + q * 4 + g;
      u16 h1u = H1b[(size_t)(m0 + rl) * 64 + col];
      float v = h1u ? t2acc[t][g] : 0.f;
      T2b[(size_t)(m0 + rl) * 64 + col] = f2bf(v);
    }
  }
}

// ---------------------------------------------------------------------------
// K5: GV = T2 W1^T (in regs only); dot, num = relu(dot + a*lyap); denom partials
__global__ __launch_bounds__(256) void k_gvdot(
    const u16* __restrict__ T2b, const u16* __restrict__ W1n,
    const float* __restrict__ LYAP, float* __restrict__ NUM, float* __restrict__ DP) {
  __shared__ u16 T2s[64 * 72];
  __shared__ u16 Bs[128 * 72];
  __shared__ float dred[4];
  const int tid = threadIdx.x;
  const int lane = tid & 63, w = tid >> 6, q = lane >> 4, r = lane & 15;
  const int m0 = blockIdx.x * 64;
  #pragma unroll
  for (int c = 0; c < 2; ++c) {
    int idx = c * 256 + tid; int a = idx >> 3, k8 = (idx & 7) * 8;
    *(short8*)&T2s[a * 72 + k8] = *(const short8*)&T2b[(size_t)(m0 + a) * 64 + k8];
  }
  float ssq[4] = {0.f, 0.f, 0.f, 0.f};
  for (int nc = 0; nc < 4; ++nc) {
    __syncthreads();
    #pragma unroll
    for (int c = 0; c < 4; ++c) {
      int idx = c * 256 + tid; int nl = idx >> 3, k8 = (idx & 7) * 8;
      *(short8*)&Bs[nl * 72 + k8] = *(const short8*)&W1n[(size_t)(nc * 128 + nl) * 64 + k8];
    }
    __syncthreads();
    f32x4 acc[8] = {};
    #pragma unroll
    for (int ks = 0; ks < 2; ++ks) {
      short8 a = *(const short8*)&T2s[(w * 16 + r) * 72 + ks * 32 + q * 8];
      #pragma unroll
      for (int t = 0; t < 8; ++t) {
        short8 b = *(const short8*)&Bs[(t * 16 + r) * 72 + ks * 32 + q * 8];
        acc[t] = MFMA(a, b, acc[t]);
      }
    }
    #pragma unroll
    for (int t = 0; t < 8; ++t)
      #pragma unroll
      for (int g = 0; g < 4; ++g) ssq[g] += acc[t][g] * acc[t][g];
  }
  float tot = 0.f;
  #pragma unroll
  for (int g = 0; g < 4; ++g) {
    float s = ssq[g];
    s += __shfl_xor(s, 1); s += __shfl_xor(s, 2); s += __shfl_xor(s, 4); s += __shfl_xor(s, 8);
    if (r == 0) {
      int rowg = m0 + w * 16 + q * 4 + g;
      float nm = s + ALPHA_C * LYAP[rowg];
      NUM[rowg] = nm > 0.f ? nm : 0.f;
    }
    s += __shfl_xor(s, 16); s += __shfl_xor(s, 32);
    tot += s;
  }
  if (lane == 0) dred[w] = tot;
  __syncthreads();
  if (tid == 0) atomicAdd(&DP[blockIdx.x & 255], dred[0] + dred[1] + dred[2] + dred[3]);
}

// ---------------------------------------------------------------------------
// K6: recompute GV from T2; out = F - (num/denom)*GV
__global__ __launch_bounds__(256) void k_out(
    const u16* __restrict__ T2b, const u16* __restrict__ W1n,
    const float* __restrict__ F, const float* __restrict__ NUM, const float* __restrict__ DP,
    float* __restrict__ out) {
  __shared__ u16 T2s[64 * 72];
  __shared__ u16 Bs[128 * 72];
  __shared__ float red[256];
  const int tid = threadIdx.x;
  const int lane = tid & 63, w = tid >> 6, q = lane >> 4, r = lane & 15;
  const int m0 = blockIdx.x * 64;
  red[tid] = DP[tid];
  #pragma unroll
  for (int c = 0; c < 2; ++c) {
    int idx = c * 256 + tid; int a = idx >> 3, k8 = (idx & 7) * 8;
    *(short8*)&T2s[a * 72 + k8] = *(const short8*)&T2b[(size_t)(m0 + a) * 64 + k8];
  }
  __syncthreads();
  for (int s = 128; s >= 1; s >>= 1) {
    if (tid < s) red[tid] += red[tid + s];
    __syncthreads();
  }
  const float inv_denom = 1.f / red[0];
  float sc[4];
  #pragma unroll
  for (int g = 0; g < 4; ++g) sc[g] = NUM[m0 + w * 16 + q * 4 + g] * inv_denom;
  for (int nc = 0; nc < 4; ++nc) {
    __syncthreads();
    #pragma unroll
    for (int c = 0; c < 4; ++c) {
      int idx = c * 256 + tid; int nl = idx >> 3, k8 = (idx & 7) * 8;
      *(short8*)&Bs[nl * 72 + k8] = *(const short8*)&W1n[(size_t)(nc * 128 + nl) * 64 + k8];
    }
    __syncthreads();
    f32x4 acc[8] = {};
    #pragma unroll
    for (int ks = 0; ks < 2; ++ks) {
      short8 a = *(const short8*)&T2s[(w * 16 + r) * 72 + ks * 32 + q * 8];
      #pragma unroll
      for (int t = 0; t < 8; ++t) {
        short8 b = *(const short8*)&Bs[(t * 16 + r) * 72 + ks * 32 + q * 8];
        acc[t] = MFMA(a, b, acc[t]);
      }
    }
    #pragma unroll
    for (int t = 0; t < 8; ++t) {
      int colg = nc * 128 + t * 16 + r;
      #pragma unroll
      for (int g = 0; g < 4; ++g) {
        size_t idx = (size_t)(m0 + w * 16 + q * 4 + g) * 512 + colg;
        out[idx] = F[idx] - sc[g] * acc[t][g];
      }
    }
  }
}

// ---------------------------------------------------------------------------
extern "C" void kernel_launch(void* const* d_in, const int* in_sizes, int n_in,
                              void* d_out, int out_size, void* d_ws, size_t ws_size,
                              hipStream_t stream) {
  const float* x  = (const float*)d_in[0];
  const float* W1 = (const float*)d_in[1];
  const float* b1 = (const float*)d_in[2];
  const float* W2 = (const float*)d_in[3];
  const float* b2 = (const float*)d_in[4];
  const float* W3 = (const float*)d_in[5];
  const float* b3 = (const float*)d_in[6];
  const float* V1 = (const float*)d_in[7];
  const float* c1 = (const float*)d_in[8];
  const float* V2 = (const float*)d_in[9];
  const float* c2 = (const float*)d_in[10];
  const float* V3 = (const float*)d_in[11];
  const float* c3 = (const float*)d_in[12];
  float* out = (float*)d_out;

  float* ws = (float*)d_ws;
  float* F     = ws;                       // 16777216 f
  float* SUMF2 = ws + 16777216;            // 32768 f
  float* LYAP  = SUMF2 + 32768;
  float* NUM   = LYAP + 32768;
  float* DP    = NUM + 32768;              // 256 f
  u16* ub   = (u16*)(DP + 256);
  u16* H1b  = ub;
  u16* H2b  = H1b + 2097152;
  u16* G1b  = H2b + 2097152;
  u16* S2b  = G1b + 2097152;
  u16* T2b  = S2b + 2097152;
  u16* W1Tb = T2b + 2097152;
  u16* W1nb = W1Tb + 32768;
  u16* W2Tb = W1nb + 32768;
  u16* W2nb = W2Tb + 4096;
  u16* W3Tb = W2nb + 4096;
  u16* W3nb = W3Tb + 32768;
  u16* V1Tb = W3nb + 32768;
  u16* V1nb = V1Tb + 32768;

  hipMemsetAsync(DP, 0, 256 * sizeof(float), stream);

  k_conv<<<128, 256, 0, stream>>>(W1, W2, W3, V1, W1Tb, W1nb, W2Tb, W2nb, W3Tb, W3nb, V1Tb, V1nb);
  k_h12<<<512, 256, 0, stream>>>(x, W1Tb, b1, W2Tb, b2, H1b, H2b);
  k_fg1<<<512, 256, 0, stream>>>(H2b, W3Tb, b3, V1Tb, c1, F, G1b, SUMF2);
  k_small<<<512, 256, 0, stream>>>(G1b, V2, c2, V3, c3, SUMF2, S2b, LYAP);
  k_ut<<<512, 256, 0, stream>>>(S2b, V1nb, F, W3nb, W2nb, H1b, H2b, T2b);
  k_gvdot<<<512, 256, 0, stream>>>(T2b, W1nb, LYAP, NUM, DP);
  k_out<<<512, 256, 0, stream>>>(T2b, W1nb, F, NUM, DP, out);
}

// Round 3
// 204.087 us; speedup vs baseline: 4.5686x; 1.3668x over previous
//
#include <hip/hip_runtime.h>

#define ALPHA_C 0.9f
#define EPS_C 1e-3f

typedef unsigned short u16;
typedef __attribute__((ext_vector_type(8))) short short8;
typedef __attribute__((ext_vector_type(4))) float f32x4;
#define MFMA(a, b, c) __builtin_amdgcn_mfma_f32_16x16x32_bf16(a, b, c, 0, 0, 0)

__device__ __forceinline__ u16 f2bf(float f) {
  union { float f; unsigned u; } v; v.f = f;
  unsigned u = v.u;
  u += 0x7FFFu + ((u >> 16) & 1u);
  return (u16)(u >> 16);
}
__device__ __forceinline__ float bf2f(u16 h) {
  union { unsigned u; float f; } v; v.u = ((unsigned)h) << 16;
  return v.f;
}

// ---------------------------------------------------------------------------
// K0: weight conversion fp32 -> bf16 (natural + transposed copies)
__global__ __launch_bounds__(256) void k_conv(
    const float* __restrict__ W1, const float* __restrict__ W2, const float* __restrict__ W3,
    const float* __restrict__ V1, const float* __restrict__ V2,
    u16* __restrict__ W1T, u16* __restrict__ W1n, u16* __restrict__ W2T, u16* __restrict__ W2n,
    u16* __restrict__ W3T, u16* __restrict__ W3n, u16* __restrict__ V1T, u16* __restrict__ V1n,
    u16* __restrict__ V2T, u16* __restrict__ V2n) {
  int i = blockIdx.x * 256 + threadIdx.x;   // 0..32767
  { float v = W1[i]; int k = i >> 6, j = i & 63; u16 b = f2bf(v); W1n[i] = b; W1T[j * 512 + k] = b; }
  { float v = V1[i]; int k = i >> 6, j = i & 63; u16 b = f2bf(v); V1n[i] = b; V1T[j * 512 + k] = b; }
  { float v = W3[i]; int k = i >> 9, n = i & 511; u16 b = f2bf(v); W3n[i] = b; W3T[n * 64 + k] = b; }
  if (i < 4096) {
    { float v = W2[i]; int k = i >> 6, j = i & 63; u16 b = f2bf(v); W2n[i] = b; W2T[j * 64 + k] = b; }
    { float v = V2[i]; int k = i >> 6, j = i & 63; u16 b = f2bf(v); V2n[i] = b; V2T[j * 64 + k] = b; }
  }
}

// ---------------------------------------------------------------------------
// K1: H1 = relu(x W1 + b1), H2 = relu(H1 W2 + b2)  -> bf16 [B,64] each
__global__ __launch_bounds__(256) void k_h12(
    const float* __restrict__ x, const u16* __restrict__ W1T, const float* __restrict__ b1,
    const u16* __restrict__ W2T, const float* __restrict__ b2,
    u16* __restrict__ H1b, u16* __restrict__ H2b) {
  __shared__ u16 As[64 * 136];
  __shared__ u16 Bs[64 * 136];
  __shared__ u16 W2s[64 * 72];
  __shared__ u16 Hs[64 * 72];
  const int tid = threadIdx.x;
  const int lane = tid & 63, w = tid >> 6, q = lane >> 4, r = lane & 15;
  const int m0 = blockIdx.x * 64;

  #pragma unroll
  for (int c = 0; c < 2; ++c) {
    int idx = c * 256 + tid; int a = idx >> 3, k8 = (idx & 7) * 8;
    *(short8*)&W2s[a * 72 + k8] = *(const short8*)&W2T[a * 64 + k8];
  }

  f32x4 acc[4] = {};
  for (int kc = 0; kc < 4; ++kc) {
    __syncthreads();
    #pragma unroll
    for (int c = 0; c < 8; ++c) {
      int idx = c * 256 + tid; int rr = idx >> 5, k4 = (idx & 31) * 4;
      float4 v = *(const float4*)&x[(size_t)(m0 + rr) * 512 + kc * 128 + k4];
      As[rr * 136 + k4 + 0] = f2bf(v.x);
      As[rr * 136 + k4 + 1] = f2bf(v.y);
      As[rr * 136 + k4 + 2] = f2bf(v.z);
      As[rr * 136 + k4 + 3] = f2bf(v.w);
    }
    #pragma unroll
    for (int c = 0; c < 4; ++c) {
      int idx = c * 256 + tid; int rr = idx >> 4, k8 = (idx & 15) * 8;
      *(short8*)&Bs[rr * 136 + k8] = *(const short8*)&W1T[rr * 512 + kc * 128 + k8];
    }
    __syncthreads();
    #pragma unroll
    for (int ks = 0; ks < 4; ++ks) {
      short8 a = *(const short8*)&As[(w * 16 + r) * 136 + ks * 32 + q * 8];
      #pragma unroll
      for (int t = 0; t < 4; ++t) {
        short8 b = *(const short8*)&Bs[(t * 16 + r) * 136 + ks * 32 + q * 8];
        acc[t] = MFMA(a, b, acc[t]);
      }
    }
  }
  __syncthreads();
  #pragma unroll
  for (int t = 0; t < 4; ++t) {
    int col = t * 16 + r; float bv = b1[col];
    #pragma unroll
    for (int g = 0; g < 4; ++g) {
      float h = acc[t][g] + bv; h = h > 0.f ? h : 0.f;
      Hs[(w * 16 + q * 4 + g) * 72 + col] = f2bf(h);
    }
  }
  __syncthreads();
  #pragma unroll
  for (int c = 0; c < 2; ++c) {
    int idx = c * 256 + tid; int rr = idx >> 3, k8 = (idx & 7) * 8;
    *(short8*)&H1b[(size_t)(m0 + rr) * 64 + k8] = *(const short8*)&Hs[rr * 72 + k8];
  }
  f32x4 acc2[4] = {};
  #pragma unroll
  for (int ks = 0; ks < 2; ++ks) {
    short8 a = *(const short8*)&Hs[(w * 16 + r) * 72 + ks * 32 + q * 8];
    #pragma unroll
    for (int t = 0; t < 4; ++t) {
      short8 b = *(const short8*)&W2s[(t * 16 + r) * 72 + ks * 32 + q * 8];
      acc2[t] = MFMA(a, b, acc2[t]);
    }
  }
  __syncthreads();
  #pragma unroll
  for (int t = 0; t < 4; ++t) {
    int col = t * 16 + r; float bv = b2[col];
    #pragma unroll
    for (int g = 0; g < 4; ++g) {
      float h = acc2[t][g] + bv; h = h > 0.f ? h : 0.f;
      Hs[(w * 16 + q * 4 + g) * 72 + col] = f2bf(h);
    }
  }
  __syncthreads();
  #pragma unroll
  for (int c = 0; c < 2; ++c) {
    int idx = c * 256 + tid; int rr = idx >> 3, k8 = (idx & 7) * 8;
    *(short8*)&H2b[(size_t)(m0 + rr) * 64 + k8] = *(const short8*)&Hs[rr * 72 + k8];
  }
}

// ---------------------------------------------------------------------------
// K2: F = H2 W3 + b3 (bf16 global); G1 = relu(F V1 + c1);
//     g2 = relu(G1 V2 + c2); s3 = mask*V3; s2 = (s3 V2^T)*mask1 -> S2b;
//     lyap = sum(g2*V3) + c3 + eps*||F||^2 -> LYAP
__global__ __launch_bounds__(256) void k_fg1s(
    const u16* __restrict__ H2b, const u16* __restrict__ W3T, const float* __restrict__ b3,
    const u16* __restrict__ V1T, const float* __restrict__ c1,
    const u16* __restrict__ V2Tb, const u16* __restrict__ V2nb, const float* __restrict__ c2,
    const float* __restrict__ V3, const float* __restrict__ c3,
    u16* __restrict__ Fb, u16* __restrict__ S2b, float* __restrict__ LYAP) {
  __shared__ u16 H2s[64 * 72];   // later reused as G1s / s3s
  __shared__ u16 Bs[128 * 72];   // also viewed as [64][136]
  __shared__ u16 As[64 * 136];   // F chunk bf16
  const int tid = threadIdx.x;
  const int lane = tid & 63, w = tid >> 6, q = lane >> 4, r = lane & 15;
  const int m0 = blockIdx.x * 64;

  #pragma unroll
  for (int c = 0; c < 2; ++c) {
    int idx = c * 256 + tid; int a = idx >> 3, k8 = (idx & 7) * 8;
    *(short8*)&H2s[a * 72 + k8] = *(const short8*)&H2b[(size_t)(m0 + a) * 64 + k8];
  }
  f32x4 g1acc[4] = {};
  float ssq[4] = {0.f, 0.f, 0.f, 0.f};
  for (int nc = 0; nc < 4; ++nc) {
    __syncthreads();
    #pragma unroll
    for (int c = 0; c < 4; ++c) {
      int idx = c * 256 + tid; int nl = idx >> 3, k8 = (idx & 7) * 8;
      *(short8*)&Bs[nl * 72 + k8] = *(const short8*)&W3T[(size_t)(nc * 128 + nl) * 64 + k8];
    }
    __syncthreads();
    f32x4 facc[8] = {};
    #pragma unroll
    for (int ks = 0; ks < 2; ++ks) {
      short8 a = *(const short8*)&H2s[(w * 16 + r) * 72 + ks * 32 + q * 8];
      #pragma unroll
      for (int t = 0; t < 8; ++t) {
        short8 b = *(const short8*)&Bs[(t * 16 + r) * 72 + ks * 32 + q * 8];
        facc[t] = MFMA(a, b, facc[t]);
      }
    }
    #pragma unroll
    for (int t = 0; t < 8; ++t) {
      int colg = nc * 128 + t * 16 + r;
      float bv = b3[colg];
      #pragma unroll
      for (int g = 0; g < 4; ++g) {
        float v = facc[t][g] + bv;
        ssq[g] += v * v;
        As[(w * 16 + q * 4 + g) * 136 + t * 16 + r] = f2bf(v);
      }
    }
    __syncthreads();
    #pragma unroll
    for (int c = 0; c < 4; ++c) {
      int idx = c * 256 + tid; int jj = idx >> 4, k8 = (idx & 15) * 8;
      *(short8*)&Bs[jj * 136 + k8] = *(const short8*)&V1T[(size_t)jj * 512 + nc * 128 + k8];
    }
    __syncthreads();
    #pragma unroll
    for (int ks = 0; ks < 4; ++ks) {
      short8 a = *(const short8*)&As[(w * 16 + r) * 136 + ks * 32 + q * 8];
      #pragma unroll
      for (int t = 0; t < 4; ++t) {
        short8 b = *(const short8*)&Bs[(t * 16 + r) * 136 + ks * 32 + q * 8];
        g1acc[t] = MFMA(a, b, g1acc[t]);
      }
    }
    // coalesced F store from As
    #pragma unroll
    for (int c = 0; c < 4; ++c) {
      int idx = c * 256 + tid; int rr = idx >> 4, k8 = (idx & 15) * 8;
      *(short8*)&Fb[(size_t)(m0 + rr) * 512 + nc * 128 + k8] = *(const short8*)&As[rr * 136 + k8];
    }
  }
  __syncthreads();   // done with H2s
  // G1 -> H2s (reuse), keep values for mask
  f32x4 g1v[4];
  #pragma unroll
  for (int t = 0; t < 4; ++t) {
    int col = t * 16 + r; float cv = c1[col];
    #pragma unroll
    for (int g = 0; g < 4; ++g) {
      float v = g1acc[t][g] + cv; v = v > 0.f ? v : 0.f;
      g1v[t][g] = v;
      H2s[(w * 16 + q * 4 + g) * 72 + col] = f2bf(v);
    }
  }
  #pragma unroll
  for (int c = 0; c < 2; ++c) {
    int idx = c * 256 + tid; int a = idx >> 3, k8 = (idx & 7) * 8;
    *(short8*)&Bs[a * 72 + k8] = *(const short8*)&V2Tb[a * 64 + k8];
  }
  __syncthreads();
  f32x4 g2acc[4] = {};
  #pragma unroll
  for (int ks = 0; ks < 2; ++ks) {
    short8 a = *(const short8*)&H2s[(w * 16 + r) * 72 + ks * 32 + q * 8];
    #pragma unroll
    for (int t = 0; t < 4; ++t) {
      short8 b = *(const short8*)&Bs[(t * 16 + r) * 72 + ks * 32 + q * 8];
      g2acc[t] = MFMA(a, b, g2acc[t]);
    }
  }
  __syncthreads();   // before overwriting H2s with s3
  float tot[4] = {0.f, 0.f, 0.f, 0.f};
  #pragma unroll
  for (int t = 0; t < 4; ++t) {
    int col = t * 16 + r;
    float c2v = c2[col], v3v = V3[col];
    #pragma unroll
    for (int g = 0; g < 4; ++g) {
      float pre = g2acc[t][g] + c2v;
      float g2 = pre > 0.f ? pre : 0.f;
      float s3 = pre > 0.f ? v3v : 0.f;
      H2s[(w * 16 + q * 4 + g) * 72 + col] = f2bf(s3);
      tot[g] += g2 * v3v;
    }
  }
  #pragma unroll
  for (int c = 0; c < 2; ++c) {
    int idx = c * 256 + tid; int a = idx >> 3, k8 = (idx & 7) * 8;
    *(short8*)&Bs[a * 72 + k8] = *(const short8*)&V2nb[a * 64 + k8];
  }
  __syncthreads();
  f32x4 s2acc[4] = {};
  #pragma unroll
  for (int ks = 0; ks < 2; ++ks) {
    short8 a = *(const short8*)&H2s[(w * 16 + r) * 72 + ks * 32 + q * 8];
    #pragma unroll
    for (int t = 0; t < 4; ++t) {
      short8 b = *(const short8*)&Bs[(t * 16 + r) * 72 + ks * 32 + q * 8];
      s2acc[t] = MFMA(a, b, s2acc[t]);
    }
  }
  #pragma unroll
  for (int t = 0; t < 4; ++t) {
    int col = t * 16 + r;
    #pragma unroll
    for (int g = 0; g < 4; ++g) {
      float sv = g1v[t][g] > 0.f ? s2acc[t][g] : 0.f;
      S2b[(size_t)(m0 + w * 16 + q * 4 + g) * 64 + col] = f2bf(sv);
    }
  }
  float c3v = c3[0];
  #pragma unroll
  for (int g = 0; g < 4; ++g) {
    float s = tot[g] + EPS_C * ssq[g];
    s += __shfl_xor(s, 1); s += __shfl_xor(s, 2); s += __shfl_xor(s, 4); s += __shfl_xor(s, 8);
    if (r == 0) LYAP[m0 + w * 16 + q * 4 + g] = s + c3v;
  }
}

// ---------------------------------------------------------------------------
// K3: U = s2 V1^T + 2eps*F ; T3 = (U W3^T)*(H2>0) ; T2 = (T3 W2^T)*(H1>0) -> T2b;
//     then GV = T2 W1^T (regs only), dot, num = relu(dot+a*lyap), denom partials
__global__ __launch_bounds__(256) void k_utg(
    const u16* __restrict__ S2b, const u16* __restrict__ V1n, const u16* __restrict__ Fb,
    const u16* __restrict__ W3n, const u16* __restrict__ W2n, const u16* __restrict__ W1n,
    const u16* __restrict__ H1b, const u16* __restrict__ H2b,
    const float* __restrict__ LYAP,
    u16* __restrict__ T2b, float* __restrict__ NUM, float* __restrict__ DP) {
  __shared__ u16 S2s[64 * 72];   // later reused as T2s
  __shared__ u16 Bs[128 * 72];   // also [64][136] view
  __shared__ u16 As[64 * 136];   // F chunk -> U chunk (in place)
  __shared__ u16 W2s[64 * 72];
  __shared__ u16 T3s[64 * 72];
  __shared__ float dred[4];
  const int tid = threadIdx.x;
  const int lane = tid & 63, w = tid >> 6, q = lane >> 4, r = lane & 15;
  const int m0 = blockIdx.x * 64;

  #pragma unroll
  for (int c = 0; c < 2; ++c) {
    int idx = c * 256 + tid; int a = idx >> 3, k8 = (idx & 7) * 8;
    *(short8*)&S2s[a * 72 + k8] = *(const short8*)&S2b[(size_t)(m0 + a) * 64 + k8];
    *(short8*)&W2s[a * 72 + k8] = *(const short8*)&W2n[a * 64 + k8];
  }
  f32x4 t3acc[4] = {};
  for (int nc = 0; nc < 4; ++nc) {
    __syncthreads();
    // F chunk -> As (coalesced), V1n chunk -> Bs
    #pragma unroll
    for (int c = 0; c < 4; ++c) {
      int idx = c * 256 + tid; int rr = idx >> 4, k8 = (idx & 15) * 8;
      *(short8*)&As[rr * 136 + k8] = *(const short8*)&Fb[(size_t)(m0 + rr) * 512 + nc * 128 + k8];
    }
    #pragma unroll
    for (int c = 0; c < 4; ++c) {
      int idx = c * 256 + tid; int nl = idx >> 3, k8 = (idx & 7) * 8;
      *(short8*)&Bs[nl * 72 + k8] = *(const short8*)&V1n[(size_t)(nc * 128 + nl) * 64 + k8];
    }
    __syncthreads();
    f32x4 uacc[8] = {};
    #pragma unroll
    for (int ks = 0; ks < 2; ++ks) {
      short8 a = *(const short8*)&S2s[(w * 16 + r) * 72 + ks * 32 + q * 8];
      #pragma unroll
      for (int t = 0; t < 8; ++t) {
        short8 b = *(const short8*)&Bs[(t * 16 + r) * 72 + ks * 32 + q * 8];
        uacc[t] = MFMA(a, b, uacc[t]);
      }
    }
    // in-place: As = bf16( uacc + 2eps * F(As) )
    #pragma unroll
    for (int t = 0; t < 8; ++t) {
      #pragma unroll
      for (int g = 0; g < 4; ++g) {
        int addr = (w * 16 + q * 4 + g) * 136 + t * 16 + r;
        As[addr] = f2bf(uacc[t][g] + 2.f * EPS_C * bf2f(As[addr]));
      }
    }
    __syncthreads();
    #pragma unroll
    for (int c = 0; c < 4; ++c) {
      int idx = c * 256 + tid; int jj = idx >> 4, k8 = (idx & 15) * 8;
      *(short8*)&Bs[jj * 136 + k8] = *(const short8*)&W3n[(size_t)jj * 512 + nc * 128 + k8];
    }
    __syncthreads();
    #pragma unroll
    for (int ks = 0; ks < 4; ++ks) {
      short8 a = *(const short8*)&As[(w * 16 + r) * 136 + ks * 32 + q * 8];
      #pragma unroll
      for (int t = 0; t < 4; ++t) {
        short8 b = *(const short8*)&Bs[(t * 16 + r) * 136 + ks * 32 + q * 8];
        t3acc[t] = MFMA(a, b, t3acc[t]);
      }
    }
  }
  #pragma unroll
  for (int t = 0; t < 4; ++t) {
    int col = t * 16 + r;
    #pragma unroll
    for (int g = 0; g < 4; ++g) {
      int rl = w * 16 + q * 4 + g;
      u16 h2u = H2b[(size_t)(m0 + rl) * 64 + col];
      float v = h2u ? t3acc[t][g] : 0.f;
      T3s[rl * 72 + col] = f2bf(v);
    }
  }
  f32x4 t2acc[4] = {};
  #pragma unroll
  for (int ks = 0; ks < 2; ++ks) {
    short8 a = *(const short8*)&T3s[(w * 16 + r) * 72 + ks * 32 + q * 8];
    #pragma unroll
    for (int t = 0; t < 4; ++t) {
      short8 b = *(const short8*)&W2s[(t * 16 + r) * 72 + ks * 32 + q * 8];
      t2acc[t] = MFMA(a, b, t2acc[t]);
    }
  }
  __syncthreads();   // all waves done with S2s (U stage) -> safe to reuse as T2s
  #pragma unroll
  for (int t = 0; t < 4; ++t) {
    int col = t * 16 + r;
    #pragma unroll
    for (int g = 0; g < 4; ++g) {
      int rl = w * 16 + q * 4 + g;
      u16 h1u = H1b[(size_t)(m0 + rl) * 64 + col];
      u16 tv = h1u ? f2bf(t2acc[t][g]) : 0;
      T2b[(size_t)(m0 + rl) * 64 + col] = tv;
      S2s[rl * 72 + col] = tv;
    }
  }
  // GV stage: ssq = ||T2 W1^T||^2 per row
  float ssq[4] = {0.f, 0.f, 0.f, 0.f};
  for (int nc = 0; nc < 4; ++nc) {
    __syncthreads();
    #pragma unroll
    for (int c = 0; c < 4; ++c) {
      int idx = c * 256 + tid; int nl = idx >> 3, k8 = (idx & 7) * 8;
      *(short8*)&Bs[nl * 72 + k8] = *(const short8*)&W1n[(size_t)(nc * 128 + nl) * 64 + k8];
    }
    __syncthreads();
    f32x4 acc[8] = {};
    #pragma unroll
    for (int ks = 0; ks < 2; ++ks) {
      short8 a = *(const short8*)&S2s[(w * 16 + r) * 72 + ks * 32 + q * 8];
      #pragma unroll
      for (int t = 0; t < 8; ++t) {
        short8 b = *(const short8*)&Bs[(t * 16 + r) * 72 + ks * 32 + q * 8];
        acc[t] = MFMA(a, b, acc[t]);
      }
    }
    #pragma unroll
    for (int t = 0; t < 8; ++t)
      #pragma unroll
      for (int g = 0; g < 4; ++g) ssq[g] += acc[t][g] * acc[t][g];
  }
  float totw = 0.f;
  #pragma unroll
  for (int g = 0; g < 4; ++g) {
    float s = ssq[g];
    s += __shfl_xor(s, 1); s += __shfl_xor(s, 2); s += __shfl_xor(s, 4); s += __shfl_xor(s, 8);
    if (r == 0) {
      int rowg = m0 + w * 16 + q * 4 + g;
      float nm = s + ALPHA_C * LYAP[rowg];
      NUM[rowg] = nm > 0.f ? nm : 0.f;
    }
    s += __shfl_xor(s, 16); s += __shfl_xor(s, 32);
    totw += s;
  }
  if (lane == 0) dred[w] = totw;
  __syncthreads();
  if (tid == 0) atomicAdd(&DP[blockIdx.x & 255], dred[0] + dred[1] + dred[2] + dred[3]);
}

// ---------------------------------------------------------------------------
// K4: recompute GV from T2; out = F - (num/denom)*GV
__global__ __launch_bounds__(256) void k_out(
    const u16* __restrict__ T2b, const u16* __restrict__ W1n,
    const u16* __restrict__ Fb, const float* __restrict__ NUM, const float* __restrict__ DP,
    float* __restrict__ out) {
  __shared__ u16 T2s[64 * 72];
  __shared__ u16 Bs[128 * 72];
  __shared__ u16 As[64 * 136];
  __shared__ float red[256];
  const int tid = threadIdx.x;
  const int lane = tid & 63, w = tid >> 6, q = lane >> 4, r = lane & 15;
  const int m0 = blockIdx.x * 64;
  red[tid] = DP[tid];
  #pragma unroll
  for (int c = 0; c < 2; ++c) {
    int idx = c * 256 + tid; int a = idx >> 3, k8 = (idx & 7) * 8;
    *(short8*)&T2s[a * 72 + k8] = *(const short8*)&T2b[(size_t)(m0 + a) * 64 + k8];
  }
  __syncthreads();
  for (int s = 128; s >= 1; s >>= 1) {
    if (tid < s) red[tid] += red[tid + s];
    __syncthreads();
  }
  const float inv_denom = 1.f / red[0];
  float sc[4];
  #pragma unroll
  for (int g = 0; g < 4; ++g) sc[g] = NUM[m0 + w * 16 + q * 4 + g] * inv_denom;
  for (int nc = 0; nc < 4; ++nc) {
    __syncthreads();
    #pragma unroll
    for (int c = 0; c < 4; ++c) {
      int idx = c * 256 + tid; int nl = idx >> 3, k8 = (idx & 7) * 8;
      *(short8*)&Bs[nl * 72 + k8] = *(const short8*)&W1n[(size_t)(nc * 128 + nl) * 64 + k8];
    }
    #pragma unroll
    for (int c = 0; c < 4; ++c) {
      int idx = c * 256 + tid; int rr = idx >> 4, k8 = (idx & 15) * 8;
      *(short8*)&As[rr * 136 + k8] = *(const short8*)&Fb[(size_t)(m0 + rr) * 512 + nc * 128 + k8];
    }
    __syncthreads();
    f32x4 acc[8] = {};
    #pragma unroll
    for (int ks = 0; ks < 2; ++ks) {
      short8 a = *(const short8*)&T2s[(w * 16 + r) * 72 + ks * 32 + q * 8];
      #pragma unroll
      for (int t = 0; t < 8; ++t) {
        short8 b = *(const short8*)&Bs[(t * 16 + r) * 72 + ks * 32 + q * 8];
        acc[t] = MFMA(a, b, acc[t]);
      }
    }
    #pragma unroll
    for (int t = 0; t < 8; ++t) {
      int colg = nc * 128 + t * 16 + r;
      #pragma unroll
      for (int g = 0; g < 4; ++g) {
        int rl = w * 16 + q * 4 + g;
        float fv = bf2f(As[rl * 136 + t * 16 + r]);
        out[(size_t)(m0 + rl) * 512 + colg] = fv - sc[g] * acc[t][g];
      }
    }
  }
}

// ---------------------------------------------------------------------------
extern "C" void kernel_launch(void* const* d_in, const int* in_sizes, int n_in,
                              void* d_out, int out_size, void* d_ws, size_t ws_size,
                              hipStream_t stream) {
  const float* x  = (const float*)d_in[0];
  const float* W1 = (const float*)d_in[1];
  const float* b1 = (const float*)d_in[2];
  const float* W2 = (const float*)d_in[3];
  const float* b2 = (const float*)d_in[4];
  const float* W3 = (const float*)d_in[5];
  const float* b3 = (const float*)d_in[6];
  const float* V1 = (const float*)d_in[7];
  const float* c1 = (const float*)d_in[8];
  const float* V2 = (const float*)d_in[9];
  const float* c2 = (const float*)d_in[10];
  const float* V3 = (const float*)d_in[11];
  const float* c3 = (const float*)d_in[12];
  float* out = (float*)d_out;

  u16* Fb = (u16*)d_ws;                       // 16777216 u16 = 32 MB
  float* LYAP = (float*)(Fb + 16777216);      // 32768 f
  float* NUM  = LYAP + 32768;
  float* DP   = NUM + 32768;                  // 256 f
  u16* H1b  = (u16*)(DP + 256);
  u16* H2b  = H1b + 2097152;
  u16* S2b  = H2b + 2097152;
  u16* T2b  = S2b + 2097152;
  u16* W1Tb = T2b + 2097152;
  u16* W1nb = W1Tb + 32768;
  u16* W2Tb = W1nb + 32768;
  u16* W2nb = W2Tb + 4096;
  u16* W3Tb = W2nb + 4096;
  u16* W3nb = W3Tb + 32768;
  u16* V1Tb = W3nb + 32768;
  u16* V1nb = V1Tb + 32768;
  u16* V2Tb = V1nb + 32768;
  u16* V2nb = V2Tb + 4096;

  hipMemsetAsync(DP, 0, 256 * sizeof(float), stream);

  k_conv<<<128, 256, 0, stream>>>(W1, W2, W3, V1, V2,
                                  W1Tb, W1nb, W2Tb, W2nb, W3Tb, W3nb, V1Tb, V1nb, V2Tb, V2nb);
  k_h12<<<512, 256, 0, stream>>>(x, W1Tb, b1, W2Tb, b2, H1b, H2b);
  k_fg1s<<<512, 256, 0, stream>>>(H2b, W3Tb, b3, V1Tb, c1, V2Tb, V2nb, c2, V3, c3, Fb, S2b, LYAP);
  k_utg<<<512, 256, 0, stream>>>(S2b, V1nb, Fb, W3nb, W2nb, W1nb, H1b, H2b, LYAP, T2b, NUM, DP);
  k_out<<<512, 256, 0, stream>>>(T2b, W1nb, Fb, NUM, DP, out);
}